// Round 15
// baseline (330.161 us; speedup 1.0000x reference)
//
#include <hip/hip_runtime.h>

#define DEV __device__ __forceinline__

typedef __attribute__((ext_vector_type(4))) float f32x4;
typedef __attribute__((ext_vector_type(8))) __bf16 bf16x8;
typedef __attribute__((ext_vector_type(8))) unsigned short u16x8;
typedef __attribute__((ext_vector_type(2))) unsigned int u32x2;

#define MFMA16(a, b, c) __builtin_amdgcn_mfma_f32_16x16x32_bf16(a, b, c, 0, 0, 0)

// ---------- helpers ----------
DEV unsigned short f2bf(float f) {
  union { float f; unsigned int u; } v; v.f = f;
  unsigned int r = v.u + 0x7fffu + ((v.u >> 16) & 1u);
  return (unsigned short)(r >> 16);
}

DEV void gl_lds16(const void* g, void* l) {
  __builtin_amdgcn_global_load_lds(
      (const __attribute__((address_space(1))) unsigned int*)g,
      (__attribute__((address_space(3))) unsigned int*)l, 16, 0, 0);
}

DEV void barrier_raw() {
  asm volatile("" ::: "memory");
  __builtin_amdgcn_s_barrier();
  asm volatile("" ::: "memory");
}

// ---------- fused weight transpose-cast: all six W[K][N] f32 -> WT[N][K] bf16 ----------
__global__ __launch_bounds__(256) void transpose_all(
    const float* __restrict__ wq, const float* __restrict__ wk,
    const float* __restrict__ wv, const float* __restrict__ wo,
    const float* __restrict__ w1, const float* __restrict__ w2,
    unsigned short* __restrict__ wqkvT, unsigned short* __restrict__ woT,
    unsigned short* __restrict__ w1T, unsigned short* __restrict__ w2T) {
  __shared__ float t[32][33];
  int id = blockIdx.x;
  const float* W; unsigned short* WT; int K, N, tile;
  if (id < 4096) {
    int m = id >> 10; tile = id & 1023; K = 1024; N = 1024;
    if (m == 0)      { W = wq; WT = wqkvT; }
    else if (m == 1) { W = wk; WT = wqkvT + 1024 * 1024; }
    else if (m == 2) { W = wv; WT = wqkvT + 2048 * 1024; }
    else             { W = wo; WT = woT; }
  } else if (id < 8192) {
    tile = id - 4096; K = 1024; N = 4096; W = w1; WT = w1T;
  } else {
    tile = id - 8192; K = 4096; N = 1024; W = w2; WT = w2T;
  }
  int ntx = N >> 5;
  int nb = (tile % ntx) * 32, kb = (tile / ntx) * 32;
  int tx = threadIdx.x & 31, ty = threadIdx.x >> 5;
#pragma unroll
  for (int i = 0; i < 4; ++i)
    t[ty + i * 8][tx] = W[(long)(kb + ty + i * 8) * N + nb + tx];
  __syncthreads();
#pragma unroll
  for (int i = 0; i < 4; ++i)
    WT[(long)(nb + ty + i * 8) * K + kb + tx] = f2bf(t[tx][ty + i * 8]);
}

// ---------- T5 bias table, log2 units, shift -24 folded, causal mask extended ----------
// bias_tab[h][idx], idx = dist + 64, dist in [-64, 1024); dist<0 -> -1e30 (masked)
__global__ __launch_bounds__(256) void prep_bias(
    const float* __restrict__ rel_table, float* __restrict__ bias_tab) {
  int idx = blockIdx.x * 256 + threadIdx.x;   // 0..1279
  int h = blockIdx.y;
  if (idx >= 1088) return;
  int dist = idx - 64;
  float v;
  if (dist < 0) v = -1e30f;
  else {
    int bucket;
    if (dist < 16) bucket = dist;
    else {
      int b2 = 16 + (int)(logf((float)dist * (1.f / 16.f)) * (16.f / logf(8.f)));
      bucket = b2 < 31 ? b2 : 31;
    }
    v = rel_table[bucket * 16 + h] * 1.4426950408889634f - 24.0f;
  }
  bias_tab[h * 1088 + idx] = v;
}

// ---------- LayerNorm f32 -> bf16, rows of 1024 ----------
__global__ __launch_bounds__(256) void ln_kernel(
    const float* __restrict__ x, const float* __restrict__ scale,
    unsigned short* __restrict__ out) {
  int row = blockIdx.x, tid = threadIdx.x;
  const float4* xr = (const float4*)(x + (long)row * 1024);
  float4 v = xr[tid];
  float s = v.x + v.y + v.z + v.w;
  float s2 = v.x * v.x + v.y * v.y + v.z * v.z + v.w * v.w;
#pragma unroll
  for (int o = 32; o > 0; o >>= 1) { s += __shfl_down(s, o); s2 += __shfl_down(s2, o); }
  __shared__ float red[8];
  __shared__ float mv[2];
  int w = tid >> 6, l = tid & 63;
  if (l == 0) { red[w] = s; red[4 + w] = s2; }
  __syncthreads();
  if (tid == 0) {
    float a = red[0] + red[1] + red[2] + red[3];
    float b = red[4] + red[5] + red[6] + red[7];
    mv[0] = a * (1.f / 1024.f); mv[1] = b * (1.f / 1024.f);
  }
  __syncthreads();
  float mu = mv[0];
  float rs = rsqrtf(mv[1] - mu * mu + 1e-6f);
  const float4* sc = (const float4*)scale;
  float4 g = sc[tid];
  unsigned int w0 = (unsigned int)f2bf((v.x - mu) * rs * g.x) |
                    ((unsigned int)f2bf((v.y - mu) * rs * g.y) << 16);
  unsigned int w1 = (unsigned int)f2bf((v.z - mu) * rs * g.z) |
                    ((unsigned int)f2bf((v.w - mu) * rs * g.w) << 16);
  u32x2 d = {w0, w1};
  *(u32x2*)(out + (long)row * 1024 + tid * 4) = d;
}

// ---------- GEMM 256x256 v5: counted-lgkm pipeline, MFMA never barrier-split ----------
// Mid barrier needs only A0/B0 reads drained (lgkmcnt(4) leaves bf1 in flight).
// af1 reads issue under the A0xB1 MFMA drain. Slots/regions/vmcnt ledger identical to v4.
template <int EPI, bool QS>
__global__ __launch_bounds__(512, 2) void gemm256(
    const unsigned short* __restrict__ A, const unsigned short* __restrict__ BT,
    const float* __restrict__ bias, const float* __restrict__ resid,
    void* __restrict__ C, int M, int N, int K) {
  __shared__ char lds[131072];
  const int tid = threadIdx.x;
  const int wid = tid >> 6, l = tid & 63, l15 = l & 15, l4 = l >> 4;
  const int nb = N >> 8;
  const int bid = (blockIdx.x & 7) * (gridDim.x >> 3) + (blockIdx.x >> 3);
  const int bx = bid % nb, by = bid / nb;
  const int row0 = by * 256, col0 = bx * 256;
  const int wr = (wid >> 2) * 128, wc = (wid & 3) * 64;
  const long lda = (long)K * 2;
  const char* Ab = (const char*)A;
  const char* Bb = (const char*)BT;
  const int NT = K >> 6;
  f32x4 acc[8][4] = {};

  auto stageA = [&](int ra, int t, int s) {
#pragma unroll
    for (int i = 0; i < 2; ++i) {
      int c = tid + i * 512;
      int lr = c >> 3;
      int r = ra * 64 + (lr & 63) + ((lr & 64) << 1);
      int cb = (c & 7) << 4;
      int lr0 = wid * 8 + i * 64;
      int r0 = ra * 64 + (lr0 & 63) + ((lr0 & 64) << 1);
      gl_lds16(Ab + (long)(row0 + r) * lda + t * 128 + (cb ^ ((r & 7) << 4)),
               lds + s * 32768 + r0 * 128);
    }
  };
  auto stageB = [&](int qb, int t, int s) {
#pragma unroll
    for (int i = 0; i < 2; ++i) {
      int c = tid + i * 512;
      int lr = c >> 3;
      int r = qb * 32 + (lr & 31) + ((lr >> 5) << 6);
      int cb = (c & 7) << 4;
      int lr0 = wid * 8 + i * 64;
      int r0 = qb * 32 + (lr0 & 31) + ((lr0 >> 5) << 6);
      gl_lds16(Bb + (long)(col0 + r) * lda + t * 128 + (cb ^ ((r & 7) << 4)),
               lds + 65536 + s * 32768 + r0 * 128);
    }
  };
  auto ldA = [&](bf16x8 (&af)[4][2], const char* As, int half) {
#pragma unroll
    for (int ks = 0; ks < 2; ++ks)
#pragma unroll
      for (int i2 = 0; i2 < 4; ++i2) {
        int r = wr + half * 64 + i2 * 16 + l15;
        af[i2][ks] = *(const bf16x8*)(As + r * 128 + ((ks * 64 + l4 * 16) ^ ((r & 7) << 4)));
      }
  };
  auto ldB = [&](bf16x8 (&bf)[2][2], const char* Bs, int half) {
#pragma unroll
    for (int ks = 0; ks < 2; ++ks)
#pragma unroll
      for (int j2 = 0; j2 < 2; ++j2) {
        int r = wc + half * 32 + j2 * 16 + l15;
        bf[j2][ks] = *(const bf16x8*)(Bs + r * 128 + ((ks * 64 + l4 * 16) ^ ((r & 7) << 4)));
      }
  };

  stageA(0, 0, 0); stageB(0, 0, 0); stageA(1, 0, 0); stageB(1, 0, 0);
  if (NT > 1) { stageA(0, 1, 1); stageB(0, 1, 1); }
  asm volatile("s_waitcnt vmcnt(4)" ::: "memory");
  barrier_raw();

  for (int n = 0; n < NT; ++n) {
    const int s = n & 1;
    const char* As = lds + s * 32768;
    const char* Bs = lds + 65536 + s * 32768;
    bf16x8 af[4][2], bf0[2][2], bf1[2][2];
    // issue A0(8), B0(4), B1(4) reads; stage A1,B1(n+1)->s^1
    ldA(af, As, 0); ldB(bf0, Bs, 0); ldB(bf1, Bs, 1);
    if (n + 1 < NT) { stageA(1, n + 1, s ^ 1); stageB(1, n + 1, s ^ 1); }
    // drain only A0/B0 (oldest 12); bf1 stays in flight across the barrier
    asm volatile("s_waitcnt lgkmcnt(4)" ::: "memory");
    barrier_raw();
    __builtin_amdgcn_s_setprio(1);
#pragma unroll
    for (int ks = 0; ks < 2; ++ks)
#pragma unroll
      for (int i2 = 0; i2 < 4; ++i2)
#pragma unroll
        for (int j2 = 0; j2 < 2; ++j2)
          acc[i2][j2] = MFMA16(af[i2][ks], bf0[j2][ks], acc[i2][j2]);
    asm volatile("s_waitcnt lgkmcnt(0)" ::: "memory");
#pragma unroll
    for (int ks = 0; ks < 2; ++ks)
#pragma unroll
      for (int i2 = 0; i2 < 4; ++i2)
#pragma unroll
        for (int j2 = 0; j2 < 2; ++j2)
          acc[i2][2 + j2] = MFMA16(af[i2][ks], bf1[j2][ks], acc[i2][2 + j2]);
    __builtin_amdgcn_s_setprio(0);
    // A1 reads (reuse af) overlap the MFMA drain; stage A0,B0(n+2)->s (A0/B0 reads drained pre-barrier)
    ldA(af, As, 1);
    if (n + 2 < NT) { stageA(0, n + 2, s); stageB(0, n + 2, s); }
    if (n == NT - 2) asm volatile("s_waitcnt vmcnt(0)" ::: "memory");
    else if (n < NT - 2) asm volatile("s_waitcnt vmcnt(4)" ::: "memory");
    asm volatile("s_waitcnt lgkmcnt(0)" ::: "memory");
    __builtin_amdgcn_s_setprio(1);
#pragma unroll
    for (int ks = 0; ks < 2; ++ks)
#pragma unroll
      for (int i2 = 0; i2 < 4; ++i2)
#pragma unroll
        for (int j2 = 0; j2 < 2; ++j2)
          acc[4 + i2][2 + j2] = MFMA16(af[i2][ks], bf1[j2][ks], acc[4 + i2][2 + j2]);
#pragma unroll
    for (int ks = 0; ks < 2; ++ks)
#pragma unroll
      for (int i2 = 0; i2 < 4; ++i2)
#pragma unroll
        for (int j2 = 0; j2 < 2; ++j2)
          acc[4 + i2][j2] = MFMA16(af[i2][ks], bf0[j2][ks], acc[4 + i2][j2]);
    __builtin_amdgcn_s_setprio(0);
    barrier_raw();
  }

#pragma unroll
  for (int j = 0; j < 4; ++j) {
    int col = col0 + wc + j * 16 + l15;
    float bv = 0.f;
    if constexpr (EPI == 1 || EPI == 3) bv = bias[col];
    float qs = 1.f;
    if constexpr (QS) qs = (col < 1024) ? 0.18033688011112042f : 1.f;
#pragma unroll
    for (int i = 0; i < 8; ++i) {
      int rbase = row0 + wr + i * 16 + l4 * 4;
#pragma unroll
      for (int r = 0; r < 4; ++r) {
        long rowm = rbase + r;
        float v = acc[i][j][r] + bv;
        if constexpr (QS) v *= qs;
        if constexpr (EPI == 1) v = fmaxf(v, 0.f);
        if constexpr (EPI == 2 || EPI == 3) v += resid[rowm * N + col];
        if constexpr (EPI == 0 || EPI == 1)
          ((unsigned short*)C)[rowm * N + col] = f2bf(v);
        else
          ((float*)C)[rowm * N + col] = v;
      }
    }
  }
}

// ---------- GEMM 256x128 v5: counted-lgkm pipeline (same structure) ----------
template <int EPI, bool QS>
__global__ __launch_bounds__(512, 2) void gemm256x128(
    const unsigned short* __restrict__ A, const unsigned short* __restrict__ BT,
    const float* __restrict__ bias, const float* __restrict__ resid,
    void* __restrict__ C, int M, int N, int K) {
  __shared__ char lds[98304];
  const int tid = threadIdx.x;
  const int wid = tid >> 6, l = tid & 63, l15 = l & 15, l4 = l >> 4;
  const int nb = N >> 7;
  const int bid = (blockIdx.x & 7) * (gridDim.x >> 3) + (blockIdx.x >> 3);
  const int bx = bid % nb, by = bid / nb;
  const int row0 = by * 256, col0 = bx * 128;
  const int wr = (wid & 3) * 64, wc = (wid >> 2) * 64;
  const long lda = (long)K * 2;
  const char* Ab = (const char*)A;
  const char* Bb = (const char*)BT;
  const int NT = K >> 6;
  f32x4 acc[4][4] = {};

  auto stageA = [&](int rq, int t, int s) {
#pragma unroll
    for (int i = 0; i < 2; ++i) {
      int c = tid + i * 512;
      int lr = c >> 3;
      int r = (lr >> 5) * 64 + rq * 32 + (lr & 31);
      int cb = (c & 7) << 4;
      int lr0 = wid * 8 + i * 64;
      int r0 = (lr0 >> 5) * 64 + rq * 32 + (lr0 & 31);
      gl_lds16(Ab + (long)(row0 + r) * lda + t * 128 + (cb ^ ((r & 7) << 4)),
               lds + s * 32768 + r0 * 128);
    }
  };
  auto stageB = [&](int cq, int t, int s) {
    int lr = tid >> 3;
    int r = (lr >> 5) * 64 + cq * 32 + (lr & 31);
    int cb = (tid & 7) << 4;
    int lr0 = wid * 8;
    int r0 = (lr0 >> 5) * 64 + cq * 32 + (lr0 & 31);
    gl_lds16(Bb + (long)(col0 + r) * lda + t * 128 + (cb ^ ((r & 7) << 4)),
             lds + 65536 + s * 16384 + r0 * 128);
  };
  auto ldA = [&](bf16x8 (&af)[2][2], const char* As, int rq) {
#pragma unroll
    for (int ks = 0; ks < 2; ++ks)
#pragma unroll
      for (int i2 = 0; i2 < 2; ++i2) {
        int r = wr + rq * 32 + i2 * 16 + l15;
        af[i2][ks] = *(const bf16x8*)(As + r * 128 + ((ks * 64 + l4 * 16) ^ ((r & 7) << 4)));
      }
  };
  auto ldB = [&](bf16x8 (&bf)[2][2], const char* Bs, int cq) {
#pragma unroll
    for (int ks = 0; ks < 2; ++ks)
#pragma unroll
      for (int j2 = 0; j2 < 2; ++j2) {
        int r = wc + cq * 32 + j2 * 16 + l15;
        bf[j2][ks] = *(const bf16x8*)(Bs + r * 128 + ((ks * 64 + l4 * 16) ^ ((r & 7) << 4)));
      }
  };

  stageA(0, 0, 0); stageB(0, 0, 0); stageA(1, 0, 0); stageB(1, 0, 0);
  if (NT > 1) { stageA(0, 1, 1); stageB(0, 1, 1); }
  asm volatile("s_waitcnt vmcnt(3)" ::: "memory");
  barrier_raw();

  for (int n = 0; n < NT; ++n) {
    const int s = n & 1;
    const char* As = lds + s * 32768;
    const char* Bs = lds + 65536 + s * 16384;
    bf16x8 af[2][2], bf0[2][2], bf1[2][2];
    // issue A0(4), B0(4), B1(4); stage A1,B1(n+1)->s^1
    ldA(af, As, 0); ldB(bf0, Bs, 0); ldB(bf1, Bs, 1);
    if (n + 1 < NT) { stageA(1, n + 1, s ^ 1); stageB(1, n + 1, s ^ 1); }
    asm volatile("s_waitcnt lgkmcnt(4)" ::: "memory");
    barrier_raw();
    __builtin_amdgcn_s_setprio(1);
#pragma unroll
    for (int ks = 0; ks < 2; ++ks)
#pragma unroll
      for (int i2 = 0; i2 < 2; ++i2)
#pragma unroll
        for (int j2 = 0; j2 < 2; ++j2)
          acc[i2][j2] = MFMA16(af[i2][ks], bf0[j2][ks], acc[i2][j2]);
    asm volatile("s_waitcnt lgkmcnt(0)" ::: "memory");
#pragma unroll
    for (int ks = 0; ks < 2; ++ks)
#pragma unroll
      for (int i2 = 0; i2 < 2; ++i2)
#pragma unroll
        for (int j2 = 0; j2 < 2; ++j2)
          acc[i2][2 + j2] = MFMA16(af[i2][ks], bf1[j2][ks], acc[i2][2 + j2]);
    __builtin_amdgcn_s_setprio(0);
    ldA(af, As, 1);
    if (n + 2 < NT) { stageA(0, n + 2, s); stageB(0, n + 2, s); }
    if (n == NT - 2) asm volatile("s_waitcnt vmcnt(0)" ::: "memory");
    else if (n < NT - 2) asm volatile("s_waitcnt vmcnt(3)" ::: "memory");
    asm volatile("s_waitcnt lgkmcnt(0)" ::: "memory");
    __builtin_amdgcn_s_setprio(1);
#pragma unroll
    for (int ks = 0; ks < 2; ++ks)
#pragma unroll
      for (int i2 = 0; i2 < 2; ++i2)
#pragma unroll
        for (int j2 = 0; j2 < 2; ++j2)
          acc[2 + i2][2 + j2] = MFMA16(af[i2][ks], bf1[j2][ks], acc[2 + i2][2 + j2]);
#pragma unroll
    for (int ks = 0; ks < 2; ++ks)
#pragma unroll
      for (int i2 = 0; i2 < 2; ++i2)
#pragma unroll
        for (int j2 = 0; j2 < 2; ++j2)
          acc[2 + i2][j2] = MFMA16(af[i2][ks], bf0[j2][ks], acc[2 + i2][j2]);
    __builtin_amdgcn_s_setprio(0);
    barrier_raw();
  }

#pragma unroll
  for (int j = 0; j < 4; ++j) {
    int co = ((j >> 1) << 5) + ((j & 1) << 4);
    int col = col0 + wc + co + l15;
    float bv = 0.f;
    if constexpr (EPI == 1 || EPI == 3) bv = bias[col];
    float qs = 1.f;
    if constexpr (QS) qs = (col < 1024) ? 0.18033688011112042f : 1.f;
#pragma unroll
    for (int i = 0; i < 4; ++i) {
      int ro = ((i >> 1) << 5) + ((i & 1) << 4);
      int rbase = row0 + wr + ro + l4 * 4;
#pragma unroll
      for (int r = 0; r < 4; ++r) {
        long rowm = rbase + r;
        float v = acc[i][j][r] + bv;
        if constexpr (QS) v *= qs;
        if constexpr (EPI == 1) v = fmaxf(v, 0.f);
        if constexpr (EPI == 2 || EPI == 3) v += resid[rowm * N + col];
        if constexpr (EPI == 0 || EPI == 1)
          ((unsigned short*)C)[rowm * N + col] = f2bf(v);
        else
          ((float*)C)[rowm * N + col] = v;
      }
    }
  }
}

// ---------- windowed attention v8: native v_exp_f32 softmax (unchanged) ----------
// qkv: [8192][3072] bf16 (Q pre-scaled by 0.125/ln2 | K | V); ao: [8192][1024] bf16
// LDS: K dbuf [2][8192] @0 | V dbuf [2][8192] @16384 | P [8][4096] @32768 | bias[1088]f32 @65536
__global__ __launch_bounds__(512, 2) void attn_kernel(
    const unsigned short* __restrict__ qkv, const float* __restrict__ bias_tab,
    unsigned short* __restrict__ ao) {
  __shared__ char lds[69888];
  const int tid = threadIdx.x;
  const int w = tid >> 6, l = tid & 63, l15 = l & 15, l4 = l >> 4;
  const int flat = blockIdx.x + 16 * blockIdx.y + 256 * blockIdx.z;
  const int f2 = (flat & 7) * 64 + (flat >> 3);
  const int bx = f2 & 15, h = (f2 >> 4) & 15, b = f2 >> 8;
  const int win = bx >> 1, qh = bx & 1;

  float* bl = (float*)(lds + 65536);
  for (int z = tid; z < 272; z += 512)
    ((float4*)bl)[z] = ((const float4*)(bias_tab + h * 1088))[z];

  // bucket saturates at 31 for dist >= 113; any idx with dist >= 128 is that constant
  const float cb = bias_tab[h * 1088 + 64 + 512];

  const int q0 = qh * 256 + w * 32;
  const long qrow0 = (long)b * 4096 + (long)win * 512;
  const char* qkvB = (const char*)qkv;

  bf16x8 qf[2][2];
#pragma unroll
  for (int j = 0; j < 2; ++j)
#pragma unroll
    for (int ks = 0; ks < 2; ++ks)
      qf[j][ks] = *(const bf16x8*)(qkv + (qrow0 + q0 + j * 16 + l15) * 3072 +
                                   h * 64 + ks * 32 + l4 * 8);

  f32x4 o[4][2] = {};
  float li[2] = {0.f, 0.f};
  const int nt_w = ((543 + q0) >> 6) + 1;
  const int nt_b = 12 + 4 * qh;
  const long s0base = (long)b * 4096 + (long)(win - 1) * 512;

  const int vkp = (tid & 31) * 2, vhd = ((tid >> 5) & 7) * 8;
  u16x8 vr0 = {}, vr1 = {};

  auto stageK = [&](int t, int buf) {
    int r = tid >> 3, cbb = (tid & 7) << 4;
    int src = cbb ^ ((r & 7) << 4);
    gl_lds16(qkvB + (s0base + t * 64 + r) * 6144 + 2048 + h * 128 + src,
             lds + buf * 8192 + w * 1024);
  };
  auto loadV = [&](int t) {
    long s0 = s0base + (long)t * 64 + vkp;
    vr0 = *(const u16x8*)(qkvB + s0 * 6144 + 4096 + h * 128 + vhd * 2);
    vr1 = *(const u16x8*)(qkvB + (s0 + 1) * 6144 + 4096 + h * 128 + vhd * 2);
  };
  auto writeV = [&](int buf) {
    char* vb = lds + 16384 + buf * 8192;
#pragma unroll
    for (int j = 0; j < 8; ++j) {
      int hd = vhd + j;
      unsigned int pk = (unsigned int)(unsigned short)vr0[j] |
                        ((unsigned int)(unsigned short)vr1[j] << 16);
      *(unsigned int*)(vb + hd * 128 + ((vkp * 2) ^ ((hd & 7) << 4))) = pk;
    }
  };

  {
    const bool v0 = (win != 0);
    if (v0) { stageK(0, 0); if (tid < 256) loadV(0); }
    asm volatile("s_waitcnt vmcnt(0)" ::: "memory");
    if (v0 && tid < 256) writeV(0);
    __syncthreads();
  }

  for (int t = 0; t < nt_b; ++t) {
    const int buf = t & 1;
    const bool nvalid = (t + 1 < nt_b) && !(win == 0 && (t + 1) < 8);
    if (nvalid) { stageK(t + 1, buf ^ 1); if (tid < 256) loadV(t + 1); }

    if (t < nt_w) {
      const bool valid = !(win == 0 && t < 8);
      // wave-uniform: min dist in this tile = 449 + q0 - 64t; >=128 -> all bucket-31
      const bool far = (449 + q0 - 64 * t) >= 128;
      f32x4 st[4][2] = {};
      if (valid) {
        __builtin_amdgcn_s_setprio(1);
#pragma unroll
        for (int ks = 0; ks < 2; ++ks) {
          bf16x8 ka[4];
#pragma unroll
          for (int i = 0; i < 4; ++i) {
            int r = i * 16 + l15;
            ka[i] = *(const bf16x8*)(lds + buf * 8192 + r * 128 +
                                     ((ks * 64 + l4 * 16) ^ ((r & 7) << 4)));
          }
#pragma unroll
          for (int i = 0; i < 4; ++i)
#pragma unroll
            for (int j = 0; j < 2; ++j)
              st[i][j] = MFMA16(ka[i], qf[j][ks], st[i][j]);
        }
        __builtin_amdgcn_s_setprio(0);
      }
#pragma unroll
      for (int j = 0; j < 2; ++j) {
        const int D1e = 576 + q0 + j * 16 + l15 - t * 64 - l4 * 4;  // idx = dist + 64
        float sv[16];
        if (far) {
#pragma unroll
          for (int i = 0; i < 4; ++i)
#pragma unroll
            for (int r = 0; r < 4; ++r)
              sv[i * 4 + r] = __builtin_amdgcn_exp2f(st[i][j][r] + cb);
        } else {
#pragma unroll
          for (int i = 0; i < 4; ++i)
#pragma unroll
            for (int r = 0; r < 4; ++r)
              sv[i * 4 + r] = __builtin_amdgcn_exp2f(st[i][j][r] + bl[D1e - i * 16 - r]);
        }
        float s0 = sv[0] + sv[1], s1 = sv[2] + sv[3];
        float s2 = sv[4] + sv[5], s3 = sv[6] + sv[7];
        float s4 = sv[8] + sv[9], s5 = sv[10] + sv[11];
        float s6 = sv[12] + sv[13], s7 = sv[14] + sv[15];
        s0 += s1; s2 += s3; s4 += s5; s6 += s7;
        float rsum = (s0 + s2) + (s4 + s6);
        rsum += __shfl_xor(rsum, 16);
        rsum += __shfl_xor(rsum, 32);
        li[j] += rsum;
        if (valid) {
          int prow = j * 16 + l15;
          char* pb = lds + 32768 + w * 4096 + prow * 128;
#pragma unroll
          for (int i = 0; i < 4; ++i) {
            unsigned int w0, w1;
            asm("v_cvt_pk_bf16_f32 %0, %1, %2" : "=v"(w0) : "v"(sv[i * 4 + 0]), "v"(sv[i * 4 + 1]));
            asm("v_cvt_pk_bf16_f32 %0, %1, %2" : "=v"(w1) : "v"(sv[i * 4 + 2]), "v"(sv[i * 4 + 3]));
            u32x2 d2 = {w0, w1};
            *(u32x2*)(pb + ((i * 32 + l4 * 8) ^ ((prow & 7) << 4))) = d2;
          }
        }
      }
      if (valid) {
        __builtin_amdgcn_s_setprio(1);
#pragma unroll
        for (int ks = 0; ks < 2; ++ks) {
          bf16x8 va[4], pf[2];
#pragma unroll
          for (int i = 0; i < 4; ++i) {
            int rr2 = i * 16 + l15;
            va[i] = *(const bf16x8*)(lds + 16384 + buf * 8192 + rr2 * 128 +
                                     ((ks * 64 + l4 * 16) ^ ((rr2 & 7) << 4)));
          }
#pragma unroll
          for (int j = 0; j < 2; ++j) {
            int rp = j * 16 + l15;
            pf[j] = *(const bf16x8*)(lds + 32768 + w * 4096 + rp * 128 +
                                     ((ks * 64 + l4 * 16) ^ ((rp & 7) << 4)));
          }
#pragma unroll
          for (int i = 0; i < 4; ++i)
#pragma unroll
            for (int j = 0; j < 2; ++j)
              o[i][j] = MFMA16(va[i], pf[j], o[i][j]);
        }
        __builtin_amdgcn_s_setprio(0);
      }
    }
    asm volatile("s_waitcnt vmcnt(0)" ::: "memory");
    if (nvalid && tid < 256) writeV(buf ^ 1);
    __syncthreads();
  }

#pragma unroll
  for (int j = 0; j < 2; ++j) {
    float inv = 1.f / li[j];
    long row = qrow0 + q0 + j * 16 + l15;
#pragma unroll
    for (int i = 0; i < 4; ++i) {
      int hd0 = i * 16 + l4 * 4;
      unsigned int w0 = (unsigned int)f2bf(o[i][j][0] * inv) |
                        ((unsigned int)f2bf(o[i][j][1] * inv) << 16);
      unsigned int w1 = (unsigned int)f2bf(o[i][j][2] * inv) |
                        ((unsigned int)f2bf(o[i][j][3] * inv) << 16);
      u32x2 d2 = {w0, w1};
      *(u32x2*)(ao + row * 1024 + h * 64 + hd0) = d2;
    }
  }
}

// ---------- launch ----------
extern "C" void kernel_launch(void* const* d_in, const int* in_sizes, int n_in,
                              void* d_out, int out_size, void* d_ws, size_t ws_size,
                              hipStream_t stream) {
  (void)in_sizes; (void)n_in; (void)out_size;
  if (ws_size < 0x8810000ULL) return;  // need ~143MB scratch

  const float* x   = (const float*)d_in[0];
  const float* wq  = (const float*)d_in[4];
  const float* wk  = (const float*)d_in[5];
  const float* wv  = (const float*)d_in[6];
  const float* wo  = (const float*)d_in[7];
  const float* ln1 = (const float*)d_in[8];
  const float* ln2 = (const float*)d_in[9];
  const float* w1  = (const float*)d_in[10];
  const float* b1  = (const float*)d_in[11];
  const float* w2  = (const float*)d_in[12];
  const float* b2  = (const float*)d_in[13];
  const float* rel = (const float*)d_in[14];

  char* ws = (char*)d_ws;
  unsigned short* wqkvT = (unsigned short*)(ws);              // [3072][1024] bf16, 6MB
  unsigned short* woT   = (unsigned short*)(ws + 0x600000);   // [1024][1024], 2MB
  unsigned short* w1T   = (unsigned short*)(ws + 0x800000);   // [4096][1024], 8MB
  unsigned short* w2T   = (unsigned short*)(ws + 0x1000000);  // [1024][4096], 8MB
  unsigned short* xn    = (unsigned short*)(ws + 0x1810000);  // [8192][1024], 16MB
  unsigned short* qkv   = (unsigned short*)(ws + 0x2810000);  // [8192][3072], 48MB
  unsigned short* hbuf  = (unsigned short*)(ws + 0x1810000);  // [8192][4096], reuses xn+qkv
  unsigned short* aob   = (unsigned short*)(ws + 0x5810000);  // [8192][1024], 16MB
  unsigned short* yn    = aob;
  float*          y     = (float*)(ws + 0x6810000);           // [8192][1024] f32, 32MB
  float*          btab  = (float*)(ws + 0x87F0000);           // [16][1088] f32, 68KB — aliases y tail:
  // prep_bias writes btab before attn; WO-GEMM overwrites it (writes all of y) only after attn.
  float*          out   = (float*)d_out;

  transpose_all<<<12288, 256, 0, stream>>>(wq, wk, wv, wo, w1, w2, wqkvT, woT, w1T, w2T);
  prep_bias<<<dim3(5, 16), 256, 0, stream>>>(rel, btab);

  ln_kernel<<<8192, 256, 0, stream>>>(x, ln1, xn);
  gemm256x128<0, true><<<32 * 24, 512, 0, stream>>>(xn, wqkvT, nullptr, nullptr, qkv, 8192, 3072, 1024);
  attn_kernel<<<dim3(16, 16, 2), 512, 0, stream>>>(qkv, btab, aob);
  gemm256x128<2, false><<<32 * 8, 512, 0, stream>>>(aob, woT, nullptr, x, y, 8192, 1024, 1024);
  ln_kernel<<<8192, 256, 0, stream>>>(y, ln2, yn);
  gemm256<1, false><<<32 * 16, 512, 0, stream>>>(yn, w1T, b1, nullptr, hbuf, 8192, 4096, 1024);
  gemm256x128<3, false><<<32 * 8, 512, 0, stream>>>(hbuf, w2T, b2, y, out, 8192, 1024, 4096);
}

// Round 16
// 327.025 us; speedup vs baseline: 1.0096x; 1.0096x over previous
//
#include <hip/hip_runtime.h>

#define DEV __device__ __forceinline__

typedef __attribute__((ext_vector_type(4))) float f32x4;
typedef __attribute__((ext_vector_type(8))) __bf16 bf16x8;
typedef __attribute__((ext_vector_type(8))) unsigned short u16x8;
typedef __attribute__((ext_vector_type(2))) unsigned int u32x2;

#define MFMA16(a, b, c) __builtin_amdgcn_mfma_f32_16x16x32_bf16(a, b, c, 0, 0, 0)

// ---------- helpers ----------
DEV unsigned short f2bf(float f) {
  union { float f; unsigned int u; } v; v.f = f;
  unsigned int r = v.u + 0x7fffu + ((v.u >> 16) & 1u);
  return (unsigned short)(r >> 16);
}

DEV void gl_lds16(const void* g, void* l) {
  __builtin_amdgcn_global_load_lds(
      (const __attribute__((address_space(1))) unsigned int*)g,
      (__attribute__((address_space(3))) unsigned int*)l, 16, 0, 0);
}

DEV void barrier_raw() {
  asm volatile("" ::: "memory");
  __builtin_amdgcn_s_barrier();
  asm volatile("" ::: "memory");
}

// ---------- fused weight transpose-cast: all six W[K][N] f32 -> WT[N][K] bf16 ----------
__global__ __launch_bounds__(256) void transpose_all(
    const float* __restrict__ wq, const float* __restrict__ wk,
    const float* __restrict__ wv, const float* __restrict__ wo,
    const float* __restrict__ w1, const float* __restrict__ w2,
    unsigned short* __restrict__ wqkvT, unsigned short* __restrict__ woT,
    unsigned short* __restrict__ w1T, unsigned short* __restrict__ w2T) {
  __shared__ float t[32][33];
  int id = blockIdx.x;
  const float* W; unsigned short* WT; int K, N, tile;
  if (id < 4096) {
    int m = id >> 10; tile = id & 1023; K = 1024; N = 1024;
    if (m == 0)      { W = wq; WT = wqkvT; }
    else if (m == 1) { W = wk; WT = wqkvT + 1024 * 1024; }
    else if (m == 2) { W = wv; WT = wqkvT + 2048 * 1024; }
    else             { W = wo; WT = woT; }
  } else if (id < 8192) {
    tile = id - 4096; K = 1024; N = 4096; W = w1; WT = w1T;
  } else {
    tile = id - 8192; K = 4096; N = 1024; W = w2; WT = w2T;
  }
  int ntx = N >> 5;
  int nb = (tile % ntx) * 32, kb = (tile / ntx) * 32;
  int tx = threadIdx.x & 31, ty = threadIdx.x >> 5;
#pragma unroll
  for (int i = 0; i < 4; ++i)
    t[ty + i * 8][tx] = W[(long)(kb + ty + i * 8) * N + nb + tx];
  __syncthreads();
#pragma unroll
  for (int i = 0; i < 4; ++i)
    WT[(long)(nb + ty + i * 8) * K + kb + tx] = f2bf(t[tx][ty + i * 8]);
}

// ---------- T5 bias table, log2 units, shift -24 folded, causal mask extended ----------
// bias_tab[h][idx], idx = dist + 64, dist in [-64, 1024); dist<0 -> -1e30 (masked)
__global__ __launch_bounds__(256) void prep_bias(
    const float* __restrict__ rel_table, float* __restrict__ bias_tab) {
  int idx = blockIdx.x * 256 + threadIdx.x;   // 0..1279
  int h = blockIdx.y;
  if (idx >= 1088) return;
  int dist = idx - 64;
  float v;
  if (dist < 0) v = -1e30f;
  else {
    int bucket;
    if (dist < 16) bucket = dist;
    else {
      int b2 = 16 + (int)(logf((float)dist * (1.f / 16.f)) * (16.f / logf(8.f)));
      bucket = b2 < 31 ? b2 : 31;
    }
    v = rel_table[bucket * 16 + h] * 1.4426950408889634f - 24.0f;
  }
  bias_tab[h * 1088 + idx] = v;
}

// ---------- LayerNorm f32 -> bf16, rows of 1024 ----------
__global__ __launch_bounds__(256) void ln_kernel(
    const float* __restrict__ x, const float* __restrict__ scale,
    unsigned short* __restrict__ out) {
  int row = blockIdx.x, tid = threadIdx.x;
  const float4* xr = (const float4*)(x + (long)row * 1024);
  float4 v = xr[tid];
  float s = v.x + v.y + v.z + v.w;
  float s2 = v.x * v.x + v.y * v.y + v.z * v.z + v.w * v.w;
#pragma unroll
  for (int o = 32; o > 0; o >>= 1) { s += __shfl_down(s, o); s2 += __shfl_down(s2, o); }
  __shared__ float red[8];
  __shared__ float mv[2];
  int w = tid >> 6, l = tid & 63;
  if (l == 0) { red[w] = s; red[4 + w] = s2; }
  __syncthreads();
  if (tid == 0) {
    float a = red[0] + red[1] + red[2] + red[3];
    float b = red[4] + red[5] + red[6] + red[7];
    mv[0] = a * (1.f / 1024.f); mv[1] = b * (1.f / 1024.f);
  }
  __syncthreads();
  float mu = mv[0];
  float rs = rsqrtf(mv[1] - mu * mu + 1e-6f);
  const float4* sc = (const float4*)scale;
  float4 g = sc[tid];
  unsigned int w0 = (unsigned int)f2bf((v.x - mu) * rs * g.x) |
                    ((unsigned int)f2bf((v.y - mu) * rs * g.y) << 16);
  unsigned int w1 = (unsigned int)f2bf((v.z - mu) * rs * g.z) |
                    ((unsigned int)f2bf((v.w - mu) * rs * g.w) << 16);
  u32x2 d = {w0, w1};
  *(u32x2*)(out + (long)row * 1024 + tid * 4) = d;
}

// ---------- GEMM 256x256 v4: merged halves, 2 barriers/K-tile, 32-MFMA clusters ----------
// lgkmcnt(0) BEFORE each barrier: all waves' fragment reads complete before anyone passes,
// so post-barrier staging can never race an in-flight ds_read. vmcnt ledger: 8 loads/thread
// per tile (A=2x2, B=2x2); prologue 12 issued -> vmcnt(4); steady vmcnt(4) at H2.
template <int EPI, bool QS>
__global__ __launch_bounds__(512, 2) void gemm256(
    const unsigned short* __restrict__ A, const unsigned short* __restrict__ BT,
    const float* __restrict__ bias, const float* __restrict__ resid,
    void* __restrict__ C, int M, int N, int K) {
  __shared__ char lds[131072];
  const int tid = threadIdx.x;
  const int wid = tid >> 6, l = tid & 63, l15 = l & 15, l4 = l >> 4;
  const int nb = N >> 8;
  const int bid = (blockIdx.x & 7) * (gridDim.x >> 3) + (blockIdx.x >> 3);
  const int bx = bid % nb, by = bid / nb;
  const int row0 = by * 256, col0 = bx * 256;
  const int wr = (wid >> 2) * 128, wc = (wid & 3) * 64;
  const long lda = (long)K * 2;
  const char* Ab = (const char*)A;
  const char* Bb = (const char*)BT;
  const int NT = K >> 6;
  f32x4 acc[8][4] = {};

  auto stageA = [&](int ra, int t, int s) {
#pragma unroll
    for (int i = 0; i < 2; ++i) {
      int c = tid + i * 512;
      int lr = c >> 3;
      int r = ra * 64 + (lr & 63) + ((lr & 64) << 1);
      int cb = (c & 7) << 4;
      int lr0 = wid * 8 + i * 64;
      int r0 = ra * 64 + (lr0 & 63) + ((lr0 & 64) << 1);
      gl_lds16(Ab + (long)(row0 + r) * lda + t * 128 + (cb ^ ((r & 7) << 4)),
               lds + s * 32768 + r0 * 128);
    }
  };
  auto stageB = [&](int qb, int t, int s) {
#pragma unroll
    for (int i = 0; i < 2; ++i) {
      int c = tid + i * 512;
      int lr = c >> 3;
      int r = qb * 32 + (lr & 31) + ((lr >> 5) << 6);
      int cb = (c & 7) << 4;
      int lr0 = wid * 8 + i * 64;
      int r0 = qb * 32 + (lr0 & 31) + ((lr0 >> 5) << 6);
      gl_lds16(Bb + (long)(col0 + r) * lda + t * 128 + (cb ^ ((r & 7) << 4)),
               lds + 65536 + s * 32768 + r0 * 128);
    }
  };
  auto ldA = [&](bf16x8 (&af)[4][2], const char* As, int half) {
#pragma unroll
    for (int ks = 0; ks < 2; ++ks)
#pragma unroll
      for (int i2 = 0; i2 < 4; ++i2) {
        int r = wr + half * 64 + i2 * 16 + l15;
        af[i2][ks] = *(const bf16x8*)(As + r * 128 + ((ks * 64 + l4 * 16) ^ ((r & 7) << 4)));
      }
  };
  auto ldB = [&](bf16x8 (&bf)[2][2], const char* Bs, int half) {
#pragma unroll
    for (int ks = 0; ks < 2; ++ks)
#pragma unroll
      for (int j2 = 0; j2 < 2; ++j2) {
        int r = wc + half * 32 + j2 * 16 + l15;
        bf[j2][ks] = *(const bf16x8*)(Bs + r * 128 + ((ks * 64 + l4 * 16) ^ ((r & 7) << 4)));
      }
  };

  stageA(0, 0, 0); stageB(0, 0, 0); stageA(1, 0, 0); stageB(1, 0, 0);
  if (NT > 1) { stageA(0, 1, 1); stageB(0, 1, 1); }
  asm volatile("s_waitcnt vmcnt(4)" ::: "memory");
  barrier_raw();

  for (int n = 0; n < NT; ++n) {
    const int s = n & 1;
    const char* As = lds + s * 32768;
    const char* Bs = lds + 65536 + s * 32768;
    bf16x8 af[4][2], bf0[2][2], bf1[2][2];
    // H1: read A0,B0,B1; stage A1,B1(n+1)->s^1; drain; BAR; MFMA A0xB0, A0xB1
    ldA(af, As, 0); ldB(bf0, Bs, 0); ldB(bf1, Bs, 1);
    if (n + 1 < NT) { stageA(1, n + 1, s ^ 1); stageB(1, n + 1, s ^ 1); }
    asm volatile("s_waitcnt lgkmcnt(0)" ::: "memory");
    barrier_raw();
    __builtin_amdgcn_s_setprio(1);
#pragma unroll
    for (int ks = 0; ks < 2; ++ks)
#pragma unroll
      for (int i2 = 0; i2 < 4; ++i2)
#pragma unroll
        for (int j2 = 0; j2 < 2; ++j2)
          acc[i2][j2] = MFMA16(af[i2][ks], bf0[j2][ks], acc[i2][j2]);
#pragma unroll
    for (int ks = 0; ks < 2; ++ks)
#pragma unroll
      for (int i2 = 0; i2 < 4; ++i2)
#pragma unroll
        for (int j2 = 0; j2 < 2; ++j2)
          acc[i2][2 + j2] = MFMA16(af[i2][ks], bf1[j2][ks], acc[i2][2 + j2]);
    __builtin_amdgcn_s_setprio(0);
    // H2: read A1; stage A0,B0(n+2)->s; vmcnt; drain; BAR; MFMA A1xB1, A1xB0
    ldA(af, As, 1);
    if (n + 2 < NT) { stageA(0, n + 2, s); stageB(0, n + 2, s); }
    if (n == NT - 2) asm volatile("s_waitcnt vmcnt(0)" ::: "memory");
    else if (n < NT - 2) asm volatile("s_waitcnt vmcnt(4)" ::: "memory");
    asm volatile("s_waitcnt lgkmcnt(0)" ::: "memory");
    barrier_raw();
    __builtin_amdgcn_s_setprio(1);
#pragma unroll
    for (int ks = 0; ks < 2; ++ks)
#pragma unroll
      for (int i2 = 0; i2 < 4; ++i2)
#pragma unroll
        for (int j2 = 0; j2 < 2; ++j2)
          acc[4 + i2][2 + j2] = MFMA16(af[i2][ks], bf1[j2][ks], acc[4 + i2][2 + j2]);
#pragma unroll
    for (int ks = 0; ks < 2; ++ks)
#pragma unroll
      for (int i2 = 0; i2 < 4; ++i2)
#pragma unroll
        for (int j2 = 0; j2 < 2; ++j2)
          acc[4 + i2][j2] = MFMA16(af[i2][ks], bf0[j2][ks], acc[4 + i2][j2]);
    __builtin_amdgcn_s_setprio(0);
  }

#pragma unroll
  for (int j = 0; j < 4; ++j) {
    int col = col0 + wc + j * 16 + l15;
    float bv = 0.f;
    if constexpr (EPI == 1 || EPI == 3) bv = bias[col];
    float qs = 1.f;
    if constexpr (QS) qs = (col < 1024) ? 0.18033688011112042f : 1.f;
#pragma unroll
    for (int i = 0; i < 8; ++i) {
      int rbase = row0 + wr + i * 16 + l4 * 4;
#pragma unroll
      for (int r = 0; r < 4; ++r) {
        long rowm = rbase + r;
        float v = acc[i][j][r] + bv;
        if constexpr (QS) v *= qs;
        if constexpr (EPI == 1) v = fmaxf(v, 0.f);
        if constexpr (EPI == 2 || EPI == 3) v += resid[rowm * N + col];
        if constexpr (EPI == 0 || EPI == 1)
          ((unsigned short*)C)[rowm * N + col] = f2bf(v);
        else
          ((float*)C)[rowm * N + col] = v;
      }
    }
  }
}

// ---------- GEMM 256x128 v4: merged halves, 2 barriers/K-tile, 16-MFMA clusters ----------
template <int EPI, bool QS>
__global__ __launch_bounds__(512, 2) void gemm256x128(
    const unsigned short* __restrict__ A, const unsigned short* __restrict__ BT,
    const float* __restrict__ bias, const float* __restrict__ resid,
    void* __restrict__ C, int M, int N, int K) {
  __shared__ char lds[98304];
  const int tid = threadIdx.x;
  const int wid = tid >> 6, l = tid & 63, l15 = l & 15, l4 = l >> 4;
  const int nb = N >> 7;
  const int bid = (blockIdx.x & 7) * (gridDim.x >> 3) + (blockIdx.x >> 3);
  const int bx = bid % nb, by = bid / nb;
  const int row0 = by * 256, col0 = bx * 128;
  const int wr = (wid & 3) * 64, wc = (wid >> 2) * 64;
  const long lda = (long)K * 2;
  const char* Ab = (const char*)A;
  const char* Bb = (const char*)BT;
  const int NT = K >> 6;
  f32x4 acc[4][4] = {};

  auto stageA = [&](int rq, int t, int s) {
#pragma unroll
    for (int i = 0; i < 2; ++i) {
      int c = tid + i * 512;
      int lr = c >> 3;
      int r = (lr >> 5) * 64 + rq * 32 + (lr & 31);
      int cb = (c & 7) << 4;
      int lr0 = wid * 8 + i * 64;
      int r0 = (lr0 >> 5) * 64 + rq * 32 + (lr0 & 31);
      gl_lds16(Ab + (long)(row0 + r) * lda + t * 128 + (cb ^ ((r & 7) << 4)),
               lds + s * 32768 + r0 * 128);
    }
  };
  auto stageB = [&](int cq, int t, int s) {
    int lr = tid >> 3;
    int r = (lr >> 5) * 64 + cq * 32 + (lr & 31);
    int cb = (tid & 7) << 4;
    int lr0 = wid * 8;
    int r0 = (lr0 >> 5) * 64 + cq * 32 + (lr0 & 31);
    gl_lds16(Bb + (long)(col0 + r) * lda + t * 128 + (cb ^ ((r & 7) << 4)),
             lds + 65536 + s * 16384 + r0 * 128);
  };
  auto ldA = [&](bf16x8 (&af)[2][2], const char* As, int rq) {
#pragma unroll
    for (int ks = 0; ks < 2; ++ks)
#pragma unroll
      for (int i2 = 0; i2 < 2; ++i2) {
        int r = wr + rq * 32 + i2 * 16 + l15;
        af[i2][ks] = *(const bf16x8*)(As + r * 128 + ((ks * 64 + l4 * 16) ^ ((r & 7) << 4)));
      }
  };
  auto ldB = [&](bf16x8 (&bf)[2][2], const char* Bs, int cq) {
#pragma unroll
    for (int ks = 0; ks < 2; ++ks)
#pragma unroll
      for (int j2 = 0; j2 < 2; ++j2) {
        int r = wc + cq * 32 + j2 * 16 + l15;
        bf[j2][ks] = *(const bf16x8*)(Bs + r * 128 + ((ks * 64 + l4 * 16) ^ ((r & 7) << 4)));
      }
  };

  stageA(0, 0, 0); stageB(0, 0, 0); stageA(1, 0, 0); stageB(1, 0, 0);
  if (NT > 1) { stageA(0, 1, 1); stageB(0, 1, 1); }
  asm volatile("s_waitcnt vmcnt(3)" ::: "memory");
  barrier_raw();

  for (int n = 0; n < NT; ++n) {
    const int s = n & 1;
    const char* As = lds + s * 32768;
    const char* Bs = lds + 65536 + s * 16384;
    bf16x8 af[2][2], bf0[2][2], bf1[2][2];
    // H1: read A0,B0,B1; stage A1,B1(n+1)->s^1; drain; BAR; MFMA A0xB0, A0xB1
    ldA(af, As, 0); ldB(bf0, Bs, 0); ldB(bf1, Bs, 1);
    if (n + 1 < NT) { stageA(1, n + 1, s ^ 1); stageB(1, n + 1, s ^ 1); }
    asm volatile("s_waitcnt lgkmcnt(0)" ::: "memory");
    barrier_raw();
    __builtin_amdgcn_s_setprio(1);
#pragma unroll
    for (int ks = 0; ks < 2; ++ks)
#pragma unroll
      for (int i2 = 0; i2 < 2; ++i2)
#pragma unroll
        for (int j2 = 0; j2 < 2; ++j2)
          acc[i2][j2] = MFMA16(af[i2][ks], bf0[j2][ks], acc[i2][j2]);
#pragma unroll
    for (int ks = 0; ks < 2; ++ks)
#pragma unroll
      for (int i2 = 0; i2 < 2; ++i2)
#pragma unroll
        for (int j2 = 0; j2 < 2; ++j2)
          acc[i2][2 + j2] = MFMA16(af[i2][ks], bf1[j2][ks], acc[i2][2 + j2]);
    __builtin_amdgcn_s_setprio(0);
    // H2: read A1; stage A0,B0(n+2)->s; vmcnt; drain; BAR; MFMA A1xB1, A1xB0
    ldA(af, As, 1);
    if (n + 2 < NT) { stageA(0, n + 2, s); stageB(0, n + 2, s); }
    if (n == NT - 2) asm volatile("s_waitcnt vmcnt(0)" ::: "memory");
    else if (n < NT - 2) asm volatile("s_waitcnt vmcnt(3)" ::: "memory");
    asm volatile("s_waitcnt lgkmcnt(0)" ::: "memory");
    barrier_raw();
    __builtin_amdgcn_s_setprio(1);
#pragma unroll
    for (int ks = 0; ks < 2; ++ks)
#pragma unroll
      for (int i2 = 0; i2 < 2; ++i2)
#pragma unroll
        for (int j2 = 0; j2 < 2; ++j2)
          acc[2 + i2][2 + j2] = MFMA16(af[i2][ks], bf1[j2][ks], acc[2 + i2][2 + j2]);
#pragma unroll
    for (int ks = 0; ks < 2; ++ks)
#pragma unroll
      for (int i2 = 0; i2 < 2; ++i2)
#pragma unroll
        for (int j2 = 0; j2 < 2; ++j2)
          acc[2 + i2][j2] = MFMA16(af[i2][ks], bf0[j2][ks], acc[2 + i2][j2]);
    __builtin_amdgcn_s_setprio(0);
  }

#pragma unroll
  for (int j = 0; j < 4; ++j) {
    int co = ((j >> 1) << 5) + ((j & 1) << 4);
    int col = col0 + wc + co + l15;
    float bv = 0.f;
    if constexpr (EPI == 1 || EPI == 3) bv = bias[col];
    float qs = 1.f;
    if constexpr (QS) qs = (col < 1024) ? 0.18033688011112042f : 1.f;
#pragma unroll
    for (int i = 0; i < 4; ++i) {
      int ro = ((i >> 1) << 5) + ((i & 1) << 4);
      int rbase = row0 + wr + ro + l4 * 4;
#pragma unroll
      for (int r = 0; r < 4; ++r) {
        long rowm = rbase + r;
        float v = acc[i][j][r] + bv;
        if constexpr (QS) v *= qs;
        if constexpr (EPI == 1) v = fmaxf(v, 0.f);
        if constexpr (EPI == 2 || EPI == 3) v += resid[rowm * N + col];
        if constexpr (EPI == 0 || EPI == 1)
          ((unsigned short*)C)[rowm * N + col] = f2bf(v);
        else
          ((float*)C)[rowm * N + col] = v;
      }
    }
  }
}

// ---------- windowed attention v8: native v_exp_f32 softmax ----------
// qkv: [8192][3072] bf16 (Q pre-scaled by 0.125/ln2 | K | V); ao: [8192][1024] bf16
// LDS: K dbuf [2][8192] @0 | V dbuf [2][8192] @16384 | P [8][4096] @32768 | bias[1088]f32 @65536
__global__ __launch_bounds__(512, 2) void attn_kernel(
    const unsigned short* __restrict__ qkv, const float* __restrict__ bias_tab,
    unsigned short* __restrict__ ao) {
  __shared__ char lds[69888];
  const int tid = threadIdx.x;
  const int w = tid >> 6, l = tid & 63, l15 = l & 15, l4 = l >> 4;
  const int flat = blockIdx.x + 16 * blockIdx.y + 256 * blockIdx.z;
  const int f2 = (flat & 7) * 64 + (flat >> 3);
  const int bx = f2 & 15, h = (f2 >> 4) & 15, b = f2 >> 8;
  const int win = bx >> 1, qh = bx & 1;

  float* bl = (float*)(lds + 65536);
  for (int z = tid; z < 272; z += 512)
    ((float4*)bl)[z] = ((const float4*)(bias_tab + h * 1088))[z];

  // bucket saturates at 31 for dist >= 113; any idx with dist >= 128 is that constant
  const float cb = bias_tab[h * 1088 + 64 + 512];

  const int q0 = qh * 256 + w * 32;
  const long qrow0 = (long)b * 4096 + (long)win * 512;
  const char* qkvB = (const char*)qkv;

  bf16x8 qf[2][2];
#pragma unroll
  for (int j = 0; j < 2; ++j)
#pragma unroll
    for (int ks = 0; ks < 2; ++ks)
      qf[j][ks] = *(const bf16x8*)(qkv + (qrow0 + q0 + j * 16 + l15) * 3072 +
                                   h * 64 + ks * 32 + l4 * 8);

  f32x4 o[4][2] = {};
  float li[2] = {0.f, 0.f};
  const int nt_w = ((543 + q0) >> 6) + 1;
  const int nt_b = 12 + 4 * qh;
  const long s0base = (long)b * 4096 + (long)(win - 1) * 512;

  const int vkp = (tid & 31) * 2, vhd = ((tid >> 5) & 7) * 8;
  u16x8 vr0 = {}, vr1 = {};

  auto stageK = [&](int t, int buf) {
    int r = tid >> 3, cbb = (tid & 7) << 4;
    int src = cbb ^ ((r & 7) << 4);
    gl_lds16(qkvB + (s0base + t * 64 + r) * 6144 + 2048 + h * 128 + src,
             lds + buf * 8192 + w * 1024);
  };
  auto loadV = [&](int t) {
    long s0 = s0base + (long)t * 64 + vkp;
    vr0 = *(const u16x8*)(qkvB + s0 * 6144 + 4096 + h * 128 + vhd * 2);
    vr1 = *(const u16x8*)(qkvB + (s0 + 1) * 6144 + 4096 + h * 128 + vhd * 2);
  };
  auto writeV = [&](int buf) {
    char* vb = lds + 16384 + buf * 8192;
#pragma unroll
    for (int j = 0; j < 8; ++j) {
      int hd = vhd + j;
      unsigned int pk = (unsigned int)(unsigned short)vr0[j] |
                        ((unsigned int)(unsigned short)vr1[j] << 16);
      *(unsigned int*)(vb + hd * 128 + ((vkp * 2) ^ ((hd & 7) << 4))) = pk;
    }
  };

  {
    const bool v0 = (win != 0);
    if (v0) { stageK(0, 0); if (tid < 256) loadV(0); }
    asm volatile("s_waitcnt vmcnt(0)" ::: "memory");
    if (v0 && tid < 256) writeV(0);
    __syncthreads();
  }

  for (int t = 0; t < nt_b; ++t) {
    const int buf = t & 1;
    const bool nvalid = (t + 1 < nt_b) && !(win == 0 && (t + 1) < 8);
    if (nvalid) { stageK(t + 1, buf ^ 1); if (tid < 256) loadV(t + 1); }

    if (t < nt_w) {
      const bool valid = !(win == 0 && t < 8);
      // wave-uniform: min dist in this tile = 449 + q0 - 64t; >=128 -> all bucket-31
      const bool far = (449 + q0 - 64 * t) >= 128;
      f32x4 st[4][2] = {};
      if (valid) {
        __builtin_amdgcn_s_setprio(1);
#pragma unroll
        for (int ks = 0; ks < 2; ++ks) {
          bf16x8 ka[4];
#pragma unroll
          for (int i = 0; i < 4; ++i) {
            int r = i * 16 + l15;
            ka[i] = *(const bf16x8*)(lds + buf * 8192 + r * 128 +
                                     ((ks * 64 + l4 * 16) ^ ((r & 7) << 4)));
          }
#pragma unroll
          for (int i = 0; i < 4; ++i)
#pragma unroll
            for (int j = 0; j < 2; ++j)
              st[i][j] = MFMA16(ka[i], qf[j][ks], st[i][j]);
        }
        __builtin_amdgcn_s_setprio(0);
      }
#pragma unroll
      for (int j = 0; j < 2; ++j) {
        const int D1e = 576 + q0 + j * 16 + l15 - t * 64 - l4 * 4;  // idx = dist + 64
        float sv[16];
        if (far) {
#pragma unroll
          for (int i = 0; i < 4; ++i)
#pragma unroll
            for (int r = 0; r < 4; ++r)
              sv[i * 4 + r] = __builtin_amdgcn_exp2f(st[i][j][r] + cb);
        } else {
#pragma unroll
          for (int i = 0; i < 4; ++i)
#pragma unroll
            for (int r = 0; r < 4; ++r)
              sv[i * 4 + r] = __builtin_amdgcn_exp2f(st[i][j][r] + bl[D1e - i * 16 - r]);
        }
        float s0 = sv[0] + sv[1], s1 = sv[2] + sv[3];
        float s2 = sv[4] + sv[5], s3 = sv[6] + sv[7];
        float s4 = sv[8] + sv[9], s5 = sv[10] + sv[11];
        float s6 = sv[12] + sv[13], s7 = sv[14] + sv[15];
        s0 += s1; s2 += s3; s4 += s5; s6 += s7;
        float rsum = (s0 + s2) + (s4 + s6);
        rsum += __shfl_xor(rsum, 16);
        rsum += __shfl_xor(rsum, 32);
        li[j] += rsum;
        if (valid) {
          int prow = j * 16 + l15;
          char* pb = lds + 32768 + w * 4096 + prow * 128;
#pragma unroll
          for (int i = 0; i < 4; ++i) {
            unsigned int w0, w1;
            asm("v_cvt_pk_bf16_f32 %0, %1, %2" : "=v"(w0) : "v"(sv[i * 4 + 0]), "v"(sv[i * 4 + 1]));
            asm("v_cvt_pk_bf16_f32 %0, %1, %2" : "=v"(w1) : "v"(sv[i * 4 + 2]), "v"(sv[i * 4 + 3]));
            u32x2 d2 = {w0, w1};
            *(u32x2*)(pb + ((i * 32 + l4 * 8) ^ ((prow & 7) << 4))) = d2;
          }
        }
      }
      if (valid) {
        __builtin_amdgcn_s_setprio(1);
#pragma unroll
        for (int ks = 0; ks < 2; ++ks) {
          bf16x8 va[4], pf[2];
#pragma unroll
          for (int i = 0; i < 4; ++i) {
            int rr2 = i * 16 + l15;
            va[i] = *(const bf16x8*)(lds + 16384 + buf * 8192 + rr2 * 128 +
                                     ((ks * 64 + l4 * 16) ^ ((rr2 & 7) << 4)));
          }
#pragma unroll
          for (int j = 0; j < 2; ++j) {
            int rp = j * 16 + l15;
            pf[j] = *(const bf16x8*)(lds + 32768 + w * 4096 + rp * 128 +
                                     ((ks * 64 + l4 * 16) ^ ((rp & 7) << 4)));
          }
#pragma unroll
          for (int i = 0; i < 4; ++i)
#pragma unroll
            for (int j = 0; j < 2; ++j)
              o[i][j] = MFMA16(va[i], pf[j], o[i][j]);
        }
        __builtin_amdgcn_s_setprio(0);
      }
    }
    asm volatile("s_waitcnt vmcnt(0)" ::: "memory");
    if (nvalid && tid < 256) writeV(buf ^ 1);
    __syncthreads();
  }

#pragma unroll
  for (int j = 0; j < 2; ++j) {
    float inv = 1.f / li[j];
    long row = qrow0 + q0 + j * 16 + l15;
#pragma unroll
    for (int i = 0; i < 4; ++i) {
      int hd0 = i * 16 + l4 * 4;
      unsigned int w0 = (unsigned int)f2bf(o[i][j][0] * inv) |
                        ((unsigned int)f2bf(o[i][j][1] * inv) << 16);
      unsigned int w1 = (unsigned int)f2bf(o[i][j][2] * inv) |
                        ((unsigned int)f2bf(o[i][j][3] * inv) << 16);
      u32x2 d2 = {w0, w1};
      *(u32x2*)(ao + row * 1024 + h * 64 + hd0) = d2;
    }
  }
}

// ---------- launch ----------
extern "C" void kernel_launch(void* const* d_in, const int* in_sizes, int n_in,
                              void* d_out, int out_size, void* d_ws, size_t ws_size,
                              hipStream_t stream) {
  (void)in_sizes; (void)n_in; (void)out_size;
  if (ws_size < 0x8810000ULL) return;  // need ~143MB scratch

  const float* x   = (const float*)d_in[0];
  const float* wq  = (const float*)d_in[4];
  const float* wk  = (const float*)d_in[5];
  const float* wv  = (const float*)d_in[6];
  const float* wo  = (const float*)d_in[7];
  const float* ln1 = (const float*)d_in[8];
  const float* ln2 = (const float*)d_in[9];
  const float* w1  = (const float*)d_in[10];
  const float* b1  = (const float*)d_in[11];
  const float* w2  = (const float*)d_in[12];
  const float* b2  = (const float*)d_in[13];
  const float* rel = (const float*)d_in[14];

  char* ws = (char*)d_ws;
  unsigned short* wqkvT = (unsigned short*)(ws);              // [3072][1024] bf16, 6MB
  unsigned short* woT   = (unsigned short*)(ws + 0x600000);   // [1024][1024], 2MB
  unsigned short* w1T   = (unsigned short*)(ws + 0x800000);   // [4096][1024], 8MB
  unsigned short* w2T   = (unsigned short*)(ws + 0x1000000);  // [1024][4096], 8MB
  unsigned short* xn    = (unsigned short*)(ws + 0x1810000);  // [8192][1024], 16MB
  unsigned short* qkv   = (unsigned short*)(ws + 0x2810000);  // [8192][3072], 48MB
  unsigned short* hbuf  = (unsigned short*)(ws + 0x1810000);  // [8192][4096], reuses xn+qkv
  unsigned short* aob   = (unsigned short*)(ws + 0x5810000);  // [8192][1024], 16MB
  unsigned short* yn    = aob;
  float*          y     = (float*)(ws + 0x6810000);           // [8192][1024] f32, 32MB
  float*          btab  = (float*)(ws + 0x87F0000);           // [16][1088] f32, 68KB — aliases y tail:
  // prep_bias writes btab before attn; WO-GEMM overwrites it (writes all of y) only after attn.
  float*          out   = (float*)d_out;

  transpose_all<<<12288, 256, 0, stream>>>(wq, wk, wv, wo, w1, w2, wqkvT, woT, w1T, w2T);
  prep_bias<<<dim3(5, 16), 256, 0, stream>>>(rel, btab);

  ln_kernel<<<8192, 256, 0, stream>>>(x, ln1, xn);
  gemm256x128<0, true><<<32 * 24, 512, 0, stream>>>(xn, wqkvT, nullptr, nullptr, qkv, 8192, 3072, 1024);
  attn_kernel<<<dim3(16, 16, 2), 512, 0, stream>>>(qkv, btab, aob);
  gemm256x128<2, false><<<32 * 8, 512, 0, stream>>>(aob, woT, nullptr, x, y, 8192, 1024, 1024);
  ln_kernel<<<8192, 256, 0, stream>>>(y, ln2, yn);
  gemm256<1, false><<<32 * 16, 512, 0, stream>>>(yn, w1T, b1, nullptr, hbuf, 8192, 4096, 1024);
  gemm256x128<3, false><<<32 * 8, 512, 0, stream>>>(hbuf, w2T, b2, y, out, 8192, 1024, 4096);
}